// Round 2
// baseline (77.473 us; speedup 1.0000x reference)
//
#include <hip/hip_runtime.h>
#include <math.h>

// Problem constants (from setup_inputs): B=16, N=8192, K=128, M=N+K=8320.
#define BB 16
#define NN 8192
#define KK 128
#define MM (NN + KK)
#define NCHUNK 32                   // 8192/256 proposal chunks per batch

// ---------------------------------------------------------------------------
// Round-6 design (resubmitted round 7 — round-6 bench died on container
// acquire, not on the kernel): SPLIT the single spin-synced kernel into two.
// Rationale: total 75.46us = ~41us harness ws-poison fill (unavoidable,
// 256 MiB @ 6.6 TB/s, top-5 of rocprof is ONLY this fill) + ~34us for
// ptl_fused. But the work model only justifies ~10-12us (VALU ~6-7us for
// 128 IoU iters incl. exact IEEE divide; ~12MB of traffic ~2us). The ~20us
// gap is attributed to the agent-scope spin: cross-XCD-coherent polls to two
// hot cache lines from 512 wave-pollers + forced exact co-residency. A
// kernel boundary on the same stream gives device-wide visibility of plain
// stores for free — no atomics, no spin, no sentinel dependence.
//
// Kernel A (ptl_iou): IoU max/argmax (verbatim loop from the validated
//   kernel — exact IEEE divide, strict > = first-max), focal weights in
//   original order, per-chunk fg counts (plain store), and {best,besti}
//   packed 8B/roi into ws.
// Kernel B (ptl_scatter): per-batch prefix over the 32 counts, re-read
//   all_rois + pack, rebuild intra-chunk ballot prefix, scatter
//   rois/labels/targets; block cx==31 writes the 128 appended-gt rows
//   closed-form (gt self-IoU == 1.0f IEEE-exact; degenerate gt -> bg).
// All numerics copied verbatim => bit-identical decisions to rounds 1-5.
// ---------------------------------------------------------------------------

__global__ __launch_bounds__(256) void ptl_iou(
    const float* __restrict__ all_rois,   // (B,N,5)
    const float* __restrict__ gt_boxes,   // (B,K,5)
    int* __restrict__ chunk_counts,       // (B,NCHUNK) in ws
    float2* __restrict__ pack,            // (B,N) {best, as_float(besti)} in ws
    float* __restrict__ out_inside,       // (B,M,4)
    float* __restrict__ out_outside)      // (B,M,4)
{
    __shared__ float4 s_box[KK];
    __shared__ int    s_w[4];

    const int b    = blockIdx.y;
    const int cx   = blockIdx.x;
    const int tid  = threadIdx.x;
    const int lane = tid & 63, wv = tid >> 6;

    // ---- stage gt table; zero-area (padding) gt -> sentinel box ----
    if (tid < KK) {
        const float* g = gt_boxes + ((size_t)b * KK + tid) * 5;
        float gx1 = g[0], gy1 = g[1], gx2 = g[2], gy2 = g[3];
        float gw = gx2 - gx1 + 1.0f, gh = gy2 - gy1 + 1.0f;
        bool z = (gw == 1.0f) && (gh == 1.0f);
        s_box[tid] = z ? make_float4(1e30f, 1e30f, -1e30f, -1e30f)
                       : make_float4(gx1, gy1, gx2 + 1.0f, gy2 + 1.0f);
    }
    __syncthreads();

    // ---- per-proposal IoU max/argmax (8192 = 32*256: all lanes valid) ----
    const int i = cx * 256 + tid;
    const float* rp_in = all_rois + ((size_t)b * NN + i) * 5;
    const float x1 = rp_in[1], y1 = rp_in[2], x2 = rp_in[3], y2 = rp_in[4];
    const float X2p = x2 + 1.0f, Y2p = y2 + 1.0f;
    const float aw = X2p - x1, ah = Y2p - y1;
    const float area_a = aw * ah;

    float best = -1e30f;
    int besti = 0;
    #pragma unroll 4
    for (int k = 0; k < KK; ++k) {
        float4 g = s_box[k];
        float area_g = (g.z - g.x) * (g.w - g.y);   // +INF for sentinel
        float iw = fmaxf(fminf(X2p, g.z) - fmaxf(x1, g.x), 0.0f);
        float ih = fmaxf(fminf(Y2p, g.w) - fmaxf(y1, g.y), 0.0f);
        float inter = iw * ih;
        float ov = inter / (area_a + area_g - inter);   // exact IEEE divide
        if (ov > best) { best = ov; besti = k; }        // strict > == first-max
    }
    if (aw == 1.0f && ah == 1.0f) { best = -1.0f; besti = 0; }  // an_zero row

    const bool fg = (best >= 0.5f);

    // ---- focal weights, ORIGINAL roi order ----
    {
        const size_t idx = (size_t)b * MM + i;
        const float om = 1.0f - best;
        const float w  = fg ? om * om : 0.0f;
        const float ow = (w > 0.0f) ? 1.0f : 0.0f;
        ((float4*)out_inside)[idx]  = make_float4(w, w, w, w);
        ((float4*)out_outside)[idx] = make_float4(ow, ow, ow, ow);
    }
    if (cx == 0 && tid < KK) {           // appended rows: weights all-zero
        const size_t idx = (size_t)b * MM + NN + tid;   // fg w=(1-1)^2=0; bg 0
        ((float4*)out_inside)[idx]  = make_float4(0.f, 0.f, 0.f, 0.f);
        ((float4*)out_outside)[idx] = make_float4(0.f, 0.f, 0.f, 0.f);
    }

    // ---- persist per-roi result for the scatter kernel ----
    pack[(size_t)b * NN + i] = make_float2(best, __int_as_float(besti));

    // ---- per-chunk fg count (plain store; kernel boundary = visibility) ----
    unsigned long long m = __ballot(fg ? 1 : 0);
    if (lane == 0) s_w[wv] = __popcll(m);
    __syncthreads();
    if (tid == 0)
        chunk_counts[b * NCHUNK + cx] = s_w[0] + s_w[1] + s_w[2] + s_w[3];
}

__global__ __launch_bounds__(256) void ptl_scatter(
    const float* __restrict__ all_rois,   // (B,N,5)
    const float* __restrict__ gt_boxes,   // (B,K,5)
    const int* __restrict__ chunk_counts, // (B,NCHUNK) in ws
    const float2* __restrict__ pack,      // (B,N) in ws
    float* __restrict__ out_rois,         // (B,M,5)
    float* __restrict__ out_labels,       // (B,M)
    float* __restrict__ out_targets)      // (B,M,4)
{
    __shared__ float4 s_box[KK];
    __shared__ float  s_lbl[KK];
    __shared__ int    s_cnt[NCHUNK];
    __shared__ int    s_gtfg[2];
    __shared__ int    s_w[4];

    const int b    = blockIdx.y;
    const int cx   = blockIdx.x;
    const int tid  = threadIdx.x;
    const int lane = tid & 63, wv = tid >> 6;

    // ---- stage gt table + nondeg counts + chunk counts ----
    bool nondeg = false;
    if (tid < KK) {
        const float* g = gt_boxes + ((size_t)b * KK + tid) * 5;
        float gx1 = g[0], gy1 = g[1], gx2 = g[2], gy2 = g[3];
        float gw = gx2 - gx1 + 1.0f, gh = gy2 - gy1 + 1.0f;
        bool z = (gw == 1.0f) && (gh == 1.0f);
        nondeg = !z;
        s_box[tid] = z ? make_float4(1e30f, 1e30f, -1e30f, -1e30f)
                       : make_float4(gx1, gy1, gx2 + 1.0f, gy2 + 1.0f);
        s_lbl[tid] = g[4];
    }
    {
        unsigned long long nm = __ballot(nondeg);   // waves 2,3: all-zero
        if (wv < 2 && lane == 0) s_gtfg[wv] = __popcll(nm);
    }
    if (tid < NCHUNK) s_cnt[tid] = chunk_counts[b * NCHUNK + tid];

    // ---- reload this roi's pack + box (overlaps the LDS latency) ----
    const int i = cx * 256 + tid;
    const float* rp_in = all_rois + ((size_t)b * NN + i) * 5;
    const float x1 = rp_in[1], y1 = rp_in[2], x2 = rp_in[3], y2 = rp_in[4];
    const float2 pk = pack[(size_t)b * NN + i];
    const float best = pk.x;
    const int   besti = __float_as_int(pk.y);
    const bool  fg = (best >= 0.5f);

    // intra-chunk exclusive prefix of fg
    unsigned long long m = __ballot(fg ? 1 : 0);
    const int lp = __popcll(m & ((1ull << lane) - 1ull));
    if (lane == 0) s_w[wv] = __popcll(m);
    __syncthreads();

    const int gtFg = s_gtfg[0] + s_gtfg[1];
    int base = 0, pTotal = 0;            // uniform across block
    for (int c = 0; c < NCHUNK; ++c) {
        int v = s_cnt[c];
        pTotal += v;
        if (c < cx) base += v;
    }
    const int total = pTotal + gtFg;

    int we = 0;
    for (int w2 = 0; w2 < wv; ++w2) we += s_w[w2];
    const int inChunkExcl = we + lp;

    // ---- scatter this block's 256 proposals ----
    {
        const int fgBefore = base + inChunkExcl;
        const int p = fg ? fgBefore : (total + i - fgBefore);

        float* rp = out_rois + ((size_t)b * MM + p) * 5;
        rp[0] = (float)b;
        rp[1] = x1; rp[2] = y1; rp[3] = x2; rp[4] = y2;

        float lbl = 0.f;
        float4 t = make_float4(0.f, 0.f, 0.f, 0.f);
        if (fg) {
            lbl = s_lbl[besti];
            if (lbl > 0.0f) {
                // fg => best >= 0.5 > 0 => besti is a real (non-sentinel) box
                float4 g = s_box[besti];
                const float gw = g.z - g.x, gh = g.w - g.y;  // gx2-gx1+1, ...
                const float gcx = g.x + 0.5f * gw, gcy = g.y + 0.5f * gh;
                const float ew = x2 - x1 + 1.0f, eh = y2 - y1 + 1.0f;
                const float ecx = x1 + 0.5f * ew, ecy = y1 + 0.5f * eh;
                t.x = ((gcx - ecx) / ew) / 0.1f;
                t.y = ((gcy - ecy) / eh) / 0.1f;
                t.z = logf(gw / ew) / 0.2f;
                t.w = logf(gh / eh) / 0.2f;
            }
        }
        out_labels[(size_t)b * MM + p] = lbl;
        ((float4*)out_targets)[(size_t)b * MM + p] = t;
    }

    // ---- writer block: the 128 appended-gt rows, closed-form ----
    if (cx == NCHUNK - 1 && tid < KK) {
        const int j = tid;
        const float* g = gt_boxes + ((size_t)b * KK + j) * 5;
        const float gx1 = g[0], gy1 = g[1], gx2 = g[2], gy2 = g[3], cls = g[4];
        const float gw = gx2 - gx1 + 1.0f, gh = gy2 - gy1 + 1.0f;
        const bool nd = !((gw == 1.0f) && (gh == 1.0f));

        // exclusive prefix of nondeg among j' < j (waves 0,1 fully active)
        unsigned long long m2 = __ballot(nd);
        int pre = __popcll(m2 & ((1ull << lane) - 1ull));
        if (wv == 1) pre += s_gtfg[0];

        const int fgBefore = pTotal + pre;   // appended come after all proposals
        const int p = nd ? fgBefore : (total + (NN + j) - fgBefore);

        float* rp = out_rois + ((size_t)b * MM + p) * 5;
        rp[0] = (float)b;
        rp[1] = gx1; rp[2] = gy1; rp[3] = gx2; rp[4] = gy2;
        // nd: max_ov=1 (self-IoU, IEEE-exact), argmax=j, label=cls, targets=0
        // !nd: an_zero -> bg, label 0, targets 0
        out_labels[(size_t)b * MM + p] = nd ? cls : 0.0f;
        ((float4*)out_targets)[(size_t)b * MM + p] = make_float4(0.f, 0.f, 0.f, 0.f);
    }
}

extern "C" void kernel_launch(void* const* d_in, const int* in_sizes, int n_in,
                              void* d_out, int out_size, void* d_ws, size_t ws_size,
                              hipStream_t stream) {
    const float* all_rois = (const float*)d_in[0];   // (B,N,5)
    const float* gt_boxes = (const float*)d_in[1];   // (B,K,5)

    float* out = (float*)d_out;
    float* out_rois    = out;                               // (B,M,5)
    float* out_labels  = out_rois    + (size_t)BB * MM * 5; // (B,M)
    float* out_targets = out_labels  + (size_t)BB * MM;     // (B,M,4)
    float* out_inside  = out_targets + (size_t)BB * MM * 4; // (B,M,4)
    float* out_outside = out_inside  + (size_t)BB * MM * 4; // (B,M,4)

    // ws layout: [0, 2KB) chunk_counts; [8KB, 8KB+1MB) per-roi pack
    int*    chunk_counts = (int*)d_ws;
    float2* pack         = (float2*)((char*)d_ws + 8192);

    ptl_iou<<<dim3(NCHUNK, BB), dim3(256, 1, 1), 0, stream>>>(
        all_rois, gt_boxes, chunk_counts, pack, out_inside, out_outside);

    ptl_scatter<<<dim3(NCHUNK, BB), dim3(256, 1, 1), 0, stream>>>(
        all_rois, gt_boxes, chunk_counts, pack,
        out_rois, out_labels, out_targets);
}

// Round 3
// 75.657 us; speedup vs baseline: 1.0240x; 1.0240x over previous
//
#include <hip/hip_runtime.h>
#include <math.h>

// Problem constants (from setup_inputs): B=16, N=8192, K=128, M=N+K=8320.
#define BB 16
#define NN 8192
#define KK 128
#define MM (NN + KK)
#define NCHUNK 32                   // 8192/256 scatter chunks per batch
#define RPB 64                      // rois per iou block (4 threads/roi)
#define NCH2 (NN / RPB)             // 128 iou sub-chunks per batch

// ---------------------------------------------------------------------------
// Round-8: attack LATENCY, not sync. Round-7 (split, no spin) was +2us vs the
// spin version -> the spin was free; the ~34us non-fill time is the IoU loop
// itself. Issue-bound floor is ~6.4us (2048 waves x 128 iters x ~27 VALU x
// 2cyc / 1024 SIMDs), so the loop is latency-bound at 2 waves/SIMD: each
// iteration has a ~70cyc dependent chain (exact IEEE divide ~9 instrs) and
// best/besti is serial across iterations.
//
// Change: 4 threads per roi, each scanning 32 gts; merge with a 2-step
// __shfl_xor butterfly taking the other lane iff (ov_o > ov) || (ov_o == ov
// && idx_o < idx) — reproduces sequential first-strict-max EXACTLY (lower gt
// range lives in lower lane; ov >= 0 always, no NaNs: denom > 0, sentinel
// boxes give ov = 0). Grid (128,16) = 2048 blocks -> up to 8 blocks/CU (was
// 2), per-thread serial span 128 -> 32 iters. Total VALU work conserved:
// latency-bound => ~3x faster; issue-bound => neutral.
//
// Scatter kernel unchanged except chunk counts are now summed 4:1 from the
// iou sub-chunks. All per-pair numerics verbatim => bit-identical results.
// ---------------------------------------------------------------------------

__global__ __launch_bounds__(256, 4) void ptl_iou(
    const float* __restrict__ all_rois,   // (B,N,5)
    const float* __restrict__ gt_boxes,   // (B,K,5)
    int* __restrict__ chunk_counts,       // (B,NCH2) in ws
    float2* __restrict__ pack,            // (B,N) {best, as_float(besti)} in ws
    float* __restrict__ out_inside,       // (B,M,4)
    float* __restrict__ out_outside)      // (B,M,4)
{
    __shared__ float4 s_box[KK];
    __shared__ int    s_w[4];

    const int b    = blockIdx.y;
    const int c2   = blockIdx.x;          // sub-chunk of 64 rois
    const int tid  = threadIdx.x;
    const int lane = tid & 63, wv = tid >> 6;
    const int sub  = tid & 3;             // which 32-gt quarter this thread scans
    const int r    = tid >> 2;            // roi within block [0,64)

    // ---- stage gt table; zero-area (padding) gt -> sentinel box ----
    if (tid < KK) {
        const float* g = gt_boxes + ((size_t)b * KK + tid) * 5;
        float gx1 = g[0], gy1 = g[1], gx2 = g[2], gy2 = g[3];
        float gw = gx2 - gx1 + 1.0f, gh = gy2 - gy1 + 1.0f;
        bool z = (gw == 1.0f) && (gh == 1.0f);
        s_box[tid] = z ? make_float4(1e30f, 1e30f, -1e30f, -1e30f)
                       : make_float4(gx1, gy1, gx2 + 1.0f, gy2 + 1.0f);
    }
    __syncthreads();

    // ---- per-(roi, gt-quarter) IoU max/argmax ----
    const int i = c2 * RPB + r;           // proposal index < NN
    const float* rp_in = all_rois + ((size_t)b * NN + i) * 5;
    const float x1 = rp_in[1], y1 = rp_in[2], x2 = rp_in[3], y2 = rp_in[4];
    const float X2p = x2 + 1.0f, Y2p = y2 + 1.0f;
    const float aw = X2p - x1, ah = Y2p - y1;
    const float area_a = aw * ah;

    float best = -1e30f;
    int besti = 0;
    const int k0 = sub << 5;
    #pragma unroll 4
    for (int kk = 0; kk < 32; ++kk) {
        const int k = k0 + kk;
        float4 g = s_box[k];
        float area_g = (g.z - g.x) * (g.w - g.y);   // +INF for sentinel
        float iw = fmaxf(fminf(X2p, g.z) - fmaxf(x1, g.x), 0.0f);
        float ih = fmaxf(fminf(Y2p, g.w) - fmaxf(y1, g.y), 0.0f);
        float inter = iw * ih;
        float ov = inter / (area_a + area_g - inter);   // exact IEEE divide
        if (ov > best) { best = ov; besti = k; }        // strict > == first-max
    }
    // ---- merge the 4 quarters: global first-strict-max ----
    #pragma unroll
    for (int mask = 1; mask <= 2; mask <<= 1) {
        float ob = __shfl_xor(best, mask);
        int   oi = __shfl_xor(besti, mask);
        if (ob > best || (ob == best && oi < besti)) { best = ob; besti = oi; }
    }
    if (aw == 1.0f && ah == 1.0f) { best = -1.0f; besti = 0; }  // an_zero row

    const bool fg = (best >= 0.5f);

    if (sub == 0) {
        // ---- focal weights, ORIGINAL roi order ----
        const size_t idx = (size_t)b * MM + i;
        const float om = 1.0f - best;
        const float w  = fg ? om * om : 0.0f;
        const float ow = (w > 0.0f) ? 1.0f : 0.0f;
        ((float4*)out_inside)[idx]  = make_float4(w, w, w, w);
        ((float4*)out_outside)[idx] = make_float4(ow, ow, ow, ow);
        // ---- persist per-roi result for the scatter kernel ----
        pack[(size_t)b * NN + i] = make_float2(best, __int_as_float(besti));
    }
    if (c2 == 0 && tid < KK) {           // appended rows: weights all-zero
        const size_t idx = (size_t)b * MM + NN + tid;   // fg w=(1-1)^2=0; bg 0
        ((float4*)out_inside)[idx]  = make_float4(0.f, 0.f, 0.f, 0.f);
        ((float4*)out_outside)[idx] = make_float4(0.f, 0.f, 0.f, 0.f);
    }

    // ---- per-sub-chunk fg count (each roi counted once via sub==0 lane) ----
    unsigned long long m = __ballot((fg && sub == 0) ? 1 : 0);
    if (lane == 0) s_w[wv] = __popcll(m);
    __syncthreads();
    if (tid == 0)
        chunk_counts[b * NCH2 + c2] = s_w[0] + s_w[1] + s_w[2] + s_w[3];
}

__global__ __launch_bounds__(256) void ptl_scatter(
    const float* __restrict__ all_rois,   // (B,N,5)
    const float* __restrict__ gt_boxes,   // (B,K,5)
    const int* __restrict__ chunk_counts, // (B,NCH2) in ws
    const float2* __restrict__ pack,      // (B,N) in ws
    float* __restrict__ out_rois,         // (B,M,5)
    float* __restrict__ out_labels,       // (B,M)
    float* __restrict__ out_targets)      // (B,M,4)
{
    __shared__ float4 s_box[KK];
    __shared__ float  s_lbl[KK];
    __shared__ int    s_cnt[NCHUNK];
    __shared__ int    s_gtfg[2];
    __shared__ int    s_w[4];

    const int b    = blockIdx.y;
    const int cx   = blockIdx.x;
    const int tid  = threadIdx.x;
    const int lane = tid & 63, wv = tid >> 6;

    // ---- stage gt table + nondeg counts + chunk counts (4:1 sum) ----
    bool nondeg = false;
    if (tid < KK) {
        const float* g = gt_boxes + ((size_t)b * KK + tid) * 5;
        float gx1 = g[0], gy1 = g[1], gx2 = g[2], gy2 = g[3];
        float gw = gx2 - gx1 + 1.0f, gh = gy2 - gy1 + 1.0f;
        bool z = (gw == 1.0f) && (gh == 1.0f);
        nondeg = !z;
        s_box[tid] = z ? make_float4(1e30f, 1e30f, -1e30f, -1e30f)
                       : make_float4(gx1, gy1, gx2 + 1.0f, gy2 + 1.0f);
        s_lbl[tid] = g[4];
    }
    {
        unsigned long long nm = __ballot(nondeg);   // waves 2,3: all-zero
        if (wv < 2 && lane == 0) s_gtfg[wv] = __popcll(nm);
    }
    if (tid < NCHUNK) {
        const int* cc = chunk_counts + b * NCH2 + tid * 4;
        s_cnt[tid] = cc[0] + cc[1] + cc[2] + cc[3];
    }

    // ---- reload this roi's pack + box (overlaps the LDS latency) ----
    const int i = cx * 256 + tid;
    const float* rp_in = all_rois + ((size_t)b * NN + i) * 5;
    const float x1 = rp_in[1], y1 = rp_in[2], x2 = rp_in[3], y2 = rp_in[4];
    const float2 pk = pack[(size_t)b * NN + i];
    const float best = pk.x;
    const int   besti = __float_as_int(pk.y);
    const bool  fg = (best >= 0.5f);

    // intra-chunk exclusive prefix of fg
    unsigned long long m = __ballot(fg ? 1 : 0);
    const int lp = __popcll(m & ((1ull << lane) - 1ull));
    if (lane == 0) s_w[wv] = __popcll(m);
    __syncthreads();

    const int gtFg = s_gtfg[0] + s_gtfg[1];
    int base = 0, pTotal = 0;            // uniform across block
    for (int c = 0; c < NCHUNK; ++c) {
        int v = s_cnt[c];
        pTotal += v;
        if (c < cx) base += v;
    }
    const int total = pTotal + gtFg;

    int we = 0;
    for (int w2 = 0; w2 < wv; ++w2) we += s_w[w2];
    const int inChunkExcl = we + lp;

    // ---- scatter this block's 256 proposals ----
    {
        const int fgBefore = base + inChunkExcl;
        const int p = fg ? fgBefore : (total + i - fgBefore);

        float* rp = out_rois + ((size_t)b * MM + p) * 5;
        rp[0] = (float)b;
        rp[1] = x1; rp[2] = y1; rp[3] = x2; rp[4] = y2;

        float lbl = 0.f;
        float4 t = make_float4(0.f, 0.f, 0.f, 0.f);
        if (fg) {
            lbl = s_lbl[besti];
            if (lbl > 0.0f) {
                // fg => best >= 0.5 > 0 => besti is a real (non-sentinel) box
                float4 g = s_box[besti];
                const float gw = g.z - g.x, gh = g.w - g.y;  // gx2-gx1+1, ...
                const float gcx = g.x + 0.5f * gw, gcy = g.y + 0.5f * gh;
                const float ew = x2 - x1 + 1.0f, eh = y2 - y1 + 1.0f;
                const float ecx = x1 + 0.5f * ew, ecy = y1 + 0.5f * eh;
                t.x = ((gcx - ecx) / ew) / 0.1f;
                t.y = ((gcy - ecy) / eh) / 0.1f;
                t.z = logf(gw / ew) / 0.2f;
                t.w = logf(gh / eh) / 0.2f;
            }
        }
        out_labels[(size_t)b * MM + p] = lbl;
        ((float4*)out_targets)[(size_t)b * MM + p] = t;
    }

    // ---- writer block: the 128 appended-gt rows, closed-form ----
    if (cx == NCHUNK - 1 && tid < KK) {
        const int j = tid;
        const float* g = gt_boxes + ((size_t)b * KK + j) * 5;
        const float gx1 = g[0], gy1 = g[1], gx2 = g[2], gy2 = g[3], cls = g[4];
        const float gw = gx2 - gx1 + 1.0f, gh = gy2 - gy1 + 1.0f;
        const bool nd = !((gw == 1.0f) && (gh == 1.0f));

        // exclusive prefix of nondeg among j' < j (waves 0,1 fully active)
        unsigned long long m2 = __ballot(nd);
        int pre = __popcll(m2 & ((1ull << lane) - 1ull));
        if (wv == 1) pre += s_gtfg[0];

        const int fgBefore = pTotal + pre;   // appended come after all proposals
        const int p = nd ? fgBefore : (total + (NN + j) - fgBefore);

        float* rp = out_rois + ((size_t)b * MM + p) * 5;
        rp[0] = (float)b;
        rp[1] = gx1; rp[2] = gy1; rp[3] = gx2; rp[4] = gy2;
        // nd: max_ov=1 (self-IoU, IEEE-exact), argmax=j, label=cls, targets=0
        // !nd: an_zero -> bg, label 0, targets 0
        out_labels[(size_t)b * MM + p] = nd ? cls : 0.0f;
        ((float4*)out_targets)[(size_t)b * MM + p] = make_float4(0.f, 0.f, 0.f, 0.f);
    }
}

extern "C" void kernel_launch(void* const* d_in, const int* in_sizes, int n_in,
                              void* d_out, int out_size, void* d_ws, size_t ws_size,
                              hipStream_t stream) {
    const float* all_rois = (const float*)d_in[0];   // (B,N,5)
    const float* gt_boxes = (const float*)d_in[1];   // (B,K,5)

    float* out = (float*)d_out;
    float* out_rois    = out;                               // (B,M,5)
    float* out_labels  = out_rois    + (size_t)BB * MM * 5; // (B,M)
    float* out_targets = out_labels  + (size_t)BB * MM;     // (B,M,4)
    float* out_inside  = out_targets + (size_t)BB * MM * 4; // (B,M,4)
    float* out_outside = out_inside  + (size_t)BB * MM * 4; // (B,M,4)

    // ws layout: [0, 8KB) chunk_counts (B*NCH2 ints); [16KB, 16KB+1MB) pack
    int*    chunk_counts = (int*)d_ws;
    float2* pack         = (float2*)((char*)d_ws + 16384);

    ptl_iou<<<dim3(NCH2, BB), dim3(256, 1, 1), 0, stream>>>(
        all_rois, gt_boxes, chunk_counts, pack, out_inside, out_outside);

    ptl_scatter<<<dim3(NCHUNK, BB), dim3(256, 1, 1), 0, stream>>>(
        all_rois, gt_boxes, chunk_counts, pack,
        out_rois, out_labels, out_targets);
}